// Round 2
// baseline (103.969 us; speedup 1.0000x reference)
//
#include <hip/hip_runtime.h>

#define Bn 4
#define Cn 64
#define Hn 64
#define Wn 64
#define TW 16   // pixels (w) per block
#define F1n 5
#define F2n 10

__global__ __launch_bounds__(256) void cam_fused_kernel(
    const float* __restrict__ x, const float* __restrict__ pv,
    const float* __restrict__ w1, const float* __restrict__ b1,
    const float* __restrict__ w2, const float* __restrict__ b2,
    float* __restrict__ out)
{
    // LDS
    __shared__ __align__(16) float xs[64 * 101];       // [c][5][20], per-c stride 101 (conflict-free)
    __shared__ __align__(16) float wgt[512];           // w1(45) b1(5) w2(450) b2(10)
    __shared__ __align__(16) float Mpad[4][64 * 12];   // per-wave M rows, padded to 12 floats
    __shared__ __align__(16) float pvs[4][64];         // per-wave proj_value column
    __shared__ __align__(16) float outs[64 * 17];      // [c][16] padded

    const int tid  = threadIdx.x;
    const int wave = tid >> 6;
    const int lane = tid & 63;        // = channel c

    const int blk = blockIdx.x;       // 0..1023
    const int b   = blk >> 8;         // 4 * 64 * 4 blocks
    const int rem = blk & 255;
    const int h   = rem >> 2;
    const int w0  = (rem & 3) << 4;

    // ---- stage weights ----
    for (int i = tid; i < 510; i += 256) {
        float v;
        if (i < 45)       v = w1[i];
        else if (i < 50)  v = b1[i - 45];
        else if (i < 500) v = w2[i - 50];
        else              v = b2[i - 500];
        wgt[i] = v;
    }

    // ---- stage x region: c 0..63, rows h-2..h+2, cols w0-2..w0+17 ----
    const float* xb = x + b * Cn * Hn * Wn;
    for (int idx = tid; idx < 64 * 100; idx += 256) {
        int c = idx / 100;
        int r = idx % 100;
        int i = r / 20, j = r % 20;
        int hh = h - 2 + i, ww = w0 - 2 + j;
        float v = 0.f;
        if ((unsigned)hh < 64u && (unsigned)ww < 64u)
            v = xb[c * Hn * Wn + hh * Wn + ww];
        xs[c * 101 + i * 20 + j] = v;
    }
    __syncthreads();

    const float* wA = wgt;         // 45
    const float* bA = wgt + 45;    // 5
    const float* wB = wgt + 50;    // 450
    const float* bB = wgt + 500;   // 10
    const float L2E = 1.4426950408889634f;

    // conv2 zero-pads its INPUT (conv1+relu output) at the spatial border:
    // conv1 output at row h-1+ih / col w-1+iw outside [0,64) must be 0,
    // NOT conv1 evaluated on zero-padded x (bias would leak through relu).
    const bool rOK0 = (h >= 1);
    const bool rOK2 = (h <= 62);

    for (int pw = 0; pw < 4; ++pw) {
        const int lw = wave * 4 + pw;   // 0..15 within tile
        const int w  = w0 + lw;
        const bool cOK0 = (w >= 1);
        const bool cOK2 = (w <= 62);

        // ---- 5x5 patch from LDS ----
        float xp[5][5];
        #pragma unroll
        for (int i = 0; i < 5; ++i)
            #pragma unroll
            for (int j = 0; j < 5; ++j)
                xp[i][j] = xs[lane * 101 + i * 20 + lw + j];

        // ---- conv1 + relu (weights hoisted per f), border-masked ----
        float r1[F1n][3][3];
        #pragma unroll
        for (int f = 0; f < F1n; ++f) {
            float wr[9];
            #pragma unroll
            for (int q = 0; q < 9; ++q) wr[q] = wA[f * 9 + q];
            const float bias = bA[f];
            #pragma unroll
            for (int ih = 0; ih < 3; ++ih) {
                const bool rok = (ih == 0) ? rOK0 : (ih == 2) ? rOK2 : true;
                #pragma unroll
                for (int iw = 0; iw < 3; ++iw) {
                    const bool cok = (iw == 0) ? cOK0 : (iw == 2) ? cOK2 : true;
                    float a = bias;
                    #pragma unroll
                    for (int i = 0; i < 3; ++i)
                        #pragma unroll
                        for (int j = 0; j < 3; ++j)
                            a = fmaf(xp[ih + i][iw + j], wr[i * 3 + j], a);
                    r1[f][ih][iw] = (rok && cok) ? fmaxf(a, 0.f) : 0.f;
                }
            }
        }

        // ---- conv2 -> t2[10] ----
        float t2[F2n];
        #pragma unroll
        for (int g = 0; g < F2n; ++g) t2[g] = bB[g];
        #pragma unroll
        for (int f = 0; f < F1n; ++f)
            #pragma unroll
            for (int ih = 0; ih < 3; ++ih)
                #pragma unroll
                for (int iw = 0; iw < 3; ++iw) {
                    const float rv = r1[f][ih][iw];
                    const int wbase = f * 9 + ih * 3 + iw;
                    #pragma unroll
                    for (int g = 0; g < F2n; ++g)
                        t2[g] = fmaf(rv, wB[g * 45 + wbase], t2[g]);
                }

        // ---- scatter into padded M (row r = k/10, col k%10, stride 12) ----
        #pragma unroll
        for (int g = 0; g < F2n; ++g) {
            const int k = g * 64 + lane;
            Mpad[wave][(k / 10) * 12 + (k % 10)] = t2[g];
        }
        pvs[wave][lane] = pv[b * Cn * Hn * Wn + lane * Hn * Wn + h * Wn + w];
        __syncthreads();

        // ---- own row (lane = c) ----
        const float4* mr4 = (const float4*)&Mpad[wave][lane * 12];
        const float4 ra = mr4[0];
        const float4 rb = mr4[1];
        const float2 rc = *(const float2*)&Mpad[wave][lane * 12 + 8];

        // ---- online softmax over d, fused with att@pv ----
        float m = -1e30f, s = 0.f, acc = 0.f;
        #pragma unroll 4
        for (int d = 0; d < 64; ++d) {
            const float4* rd4 = (const float4*)&Mpad[wave][d * 12];
            const float4 da = rd4[0];
            const float4 db = rd4[1];
            const float2 dc = *(const float2*)&Mpad[wave][d * 12 + 8];
            float e = ra.x * da.x;
            e = fmaf(ra.y, da.y, e);
            e = fmaf(ra.z, da.z, e);
            e = fmaf(ra.w, da.w, e);
            e = fmaf(rb.x, db.x, e);
            e = fmaf(rb.y, db.y, e);
            e = fmaf(rb.z, db.z, e);
            e = fmaf(rb.w, db.w, e);
            e = fmaf(rc.x, dc.x, e);
            e = fmaf(rc.y, dc.y, e);
            const float mn = fmaxf(m, e);
            const float sc = exp2f((m - mn) * L2E);
            const float p  = exp2f((e - mn) * L2E);
            s   = fmaf(s, sc, p);
            acc = fmaf(acc, sc, p * pvs[wave][d]);
            m = mn;
        }
        outs[lane * 17 + lw] = acc / s;
        __syncthreads();   // protect Mpad for next pixel + publish outs
    }

    // ---- coalesced output write: [64][16] tile -> out[b, c, h, w0..w0+15] ----
    {
        const int c   = tid >> 2;
        const int seg = (tid & 3) << 2;
        float4 v;
        v.x = outs[c * 17 + seg + 0];
        v.y = outs[c * 17 + seg + 1];
        v.z = outs[c * 17 + seg + 2];
        v.w = outs[c * 17 + seg + 3];
        *(float4*)&out[b * Cn * Hn * Wn + c * Hn * Wn + h * Wn + w0 + seg] = v;
    }
}

extern "C" void kernel_launch(void* const* d_in, const int* in_sizes, int n_in,
                              void* d_out, int out_size, void* d_ws, size_t ws_size,
                              hipStream_t stream) {
    const float* x  = (const float*)d_in[0];
    const float* pv = (const float*)d_in[1];
    const float* w1 = (const float*)d_in[2];
    const float* b1 = (const float*)d_in[3];
    const float* w2 = (const float*)d_in[4];
    const float* b2 = (const float*)d_in[5];
    float* out = (float*)d_out;

    dim3 grid(Bn * Hn * (Wn / TW));   // 1024
    dim3 block(256);
    hipLaunchKernelGGL(cam_fused_kernel, grid, block, 0, stream,
                       x, pv, w1, b1, w2, b2, out);
}